// Round 17
// baseline (1110.692 us; speedup 1.0000x reference)
//
#include <hip/hip_runtime.h>
#include <hip/hip_bf16.h>
#include <hip/hip_cooperative_groups.h>
#include <math.h>

namespace cg = cooperative_groups;

#define BB 8
#define SS 1024
#define EE 256
#define HH 8
#define DKK 32
#define LL 4
#define FF 1024
#define NQQ 256
#define CC 10

typedef __attribute__((ext_vector_type(8))) short short8;
typedef __attribute__((ext_vector_type(4))) short s16x4;
typedef __attribute__((ext_vector_type(4))) float f32x4;

static __device__ __forceinline__ f32x4 mfma16(short8 a, short8 b, f32x4 c) {
    return __builtin_amdgcn_mfma_f32_16x16x32_bf16(a, b, c, 0, 0, 0);
}
static __device__ __forceinline__ short f2bf(float f) {
    __hip_bfloat16 h = __float2bfloat16(f);
    return *reinterpret_cast<short*>(&h);
}

// Fragment-packed layout: P[(tile*KG + kg)*64 + lane] (short8 units).
#define FRAG(P, tile, KG, kg, l) ((P) + (((size_t)((tile)*(KG) + (kg)))*64 + (l))*8)
// accP flat index: [qg][slot][q][c] with c-stride 264
#define ACCP(qg, s, q, c) accP[((((qg)*2+(s))*16+(q))*264) + (c)]

// ---------------------------------------------------------------------------
// qproj from an LDS row (stride-268 f32): thread handles one (s,h).
// ---------------------------------------------------------------------------
static __device__ __forceinline__ void qproj_row(
        const float* __restrict__ xrow,
        const float* __restrict__ th,
        int b, int s, int h,
        short* __restrict__ PQ, short* __restrict__ PT) {
    float v[DKK];
    float cum = __cosf(xrow[h * DKK + 0] + th[0]);
    float prod1 = 1.0f;
    #pragma unroll
    for (int j = 1; j < DKK; ++j) {
        float c = __cosf(xrow[h * DKK + j] + th[j]);
        cum *= c;
        prod1 *= c;
        v[j] = cum;
    }
    v[0] = prod1;
    short* pq = PQ + (size_t)b * SS * EE;
    int stile = s >> 4, lr = s & 15;
    #pragma unroll
    for (int lg = 0; lg < 4; ++lg) {
        short8 u;
        #pragma unroll
        for (int j = 0; j < 8; ++j) u[j] = f2bf(v[lg*8 + j]);
        *(short8*)FRAG(pq, stile*8 + h, 1, 0, lg*16 + lr) = u;
    }
    short* pt = PT + (size_t)b * SS * EE;
    int kt = s >> 5, lgs = (s >> 3) & 3, j0 = s & 7;
    #pragma unroll
    for (int j = 0; j < DKK; ++j) {
        int e = h * DKK + j;
        FRAG(pt, e >> 4, 32, kt, lgs*16 + (e & 15))[j0] = f2bf(v[j]);
    }
}

// ---------------------------------------------------------------------------
// Kernel 1: MERGED prep. bid<2304: weight transpose/pack. bid>=2304: embed +
// pos-encoding + layer-0 qproj (16 tokens/block, 256 thr).
// ---------------------------------------------------------------------------
__global__ __launch_bounds__(256) void k_prep(
        const float* __restrict__ W1, const float* __restrict__ W2,
        const float* __restrict__ Wc,
        short* __restrict__ W1P, short* __restrict__ W2P, short* __restrict__ WcP,
        const int* __restrict__ tokens, const float* __restrict__ emb,
        const float* __restrict__ theta_q,
        float* __restrict__ x, short* __restrict__ PQ, short* __restrict__ PT) {
    __shared__ float shmem[16 * 268];
    const int t = threadIdx.x;
    if (blockIdx.x < 2304) {
        int bid = blockIdx.x;
        int lyr = bid / 576, rem = bid % 576;
        const float* in; short* out; int R, C, tile;
        if (rem < 256)      { in = W1 + (size_t)lyr*NQQ*FF; out = W1P + (size_t)lyr*FF*NQQ; R = NQQ; C = FF;  tile = rem; }
        else if (rem < 512) { in = W2 + (size_t)lyr*FF*EE;  out = W2P + (size_t)lyr*EE*FF;  R = FF;  C = EE;  tile = rem - 256; }
        else                { in = Wc + (size_t)lyr*EE*EE;  out = WcP + (size_t)lyr*EE*EE;  R = EE;  C = EE;  tile = rem - 512; }
        const int KG = R >> 5;
        int tiles_c = C >> 5;
        int tc = tile % tiles_c, tr = tile / tiles_c;
        float (*tl)[33] = (float(*)[33])shmem;
        int rr = t >> 5, cc = t & 31;
        #pragma unroll
        for (int i = 0; i < 4; ++i)
            tl[rr + i*8][cc] = in[(size_t)(tr*32 + rr + i*8) * C + tc*32 + cc];
        __syncthreads();
        int ro = t >> 3, co = (t & 7) * 4;
        int n = tc*32 + ro;
        int k = tr*32 + co;
        int ntile = n >> 4, lr = n & 15;
        int kg = k >> 5, lg = (k & 31) >> 3, j0 = k & 7;
        s16x4 v;
        v[0] = f2bf(tl[co + 0][ro]);
        v[1] = f2bf(tl[co + 1][ro]);
        v[2] = f2bf(tl[co + 2][ro]);
        v[3] = f2bf(tl[co + 3][ro]);
        *(s16x4*)(FRAG(out, ntile, KG, kg, lg*16 + lr) + j0) = v;
    } else {
        int blk = blockIdx.x - 2304;
        int bsw = blk & 7, local = blk >> 3;        // batch -> XCD
        int tok0 = bsw * SS + local * 16;
        {
            int r = t >> 4, c0 = (t & 15) * 16;
            int bs = tok0 + r;
            int s  = bs & (SS - 1);
            int tok = tokens[bs];
            const float* er = emb + (size_t)tok * EE + c0;
            float vals[16];
            #pragma unroll
            for (int i = 0; i < 16; ++i) {
                int col = c0 + i;
                int i2 = col >> 1;
                float div = __expf(-(float)(2 * i2) * (logf(10000.0f) / (float)EE));
                float ang = (float)s * div;
                float pe = (col & 1) ? __cosf(ang) : __sinf(ang);
                vals[i] = er[i] + pe;
                shmem[r * 268 + col] = vals[i];
            }
            float* xg = x + (size_t)bs * EE + c0;
            #pragma unroll
            for (int i4 = 0; i4 < 4; ++i4)
                *(float4*)(xg + i4 * 4) = *(const float4*)&vals[i4 * 4];
        }
        __syncthreads();
        if (t < 128) {
            int sl = t >> 3, h = t & 7;
            int bs = tok0 + sl;
            qproj_row(&shmem[sl * 268], theta_q + h * DKK,
                      bs >> 10, bs & (SS - 1), h, PQ, PT);
        }
    }
}

// ---------------------------------------------------------------------------
// Kernel 2: PERSISTENT cooperative layer kernel. 256 blocks x 1024 thr
// (1 block/CU). Each block owns 32 tokens of batch b = blk&7 (XCD-pinned).
// Per layer: attn (waves 0-7, 2 q-tiles, KV-split, no online softmax,
// y -> LDS) ; wcffn (16 waves: wc+LN1+FFN+LN2, x kept in LDS across layers,
// next-layer qproj -> ping-pong PQ/PT) ; ONE grid.sync per layer.
// ---------------------------------------------------------------------------
__global__ __launch_bounds__(1024, 4) void k_layers(
        short* __restrict__ PQ0, short* __restrict__ PT0,
        short* __restrict__ PQ1, short* __restrict__ PT1,
        const short* __restrict__ WcP, const short* __restrict__ W1P,
        const short* __restrict__ W2P,
        const float* __restrict__ bc, const float* __restrict__ g1,
        const float* __restrict__ bn1, const float* __restrict__ theta_ffn,
        const float* __restrict__ b1, const float* __restrict__ b2,
        const float* __restrict__ g2, const float* __restrict__ bn2,
        const float* __restrict__ theta_attn, const float* __restrict__ x,
        float* __restrict__ hpart) {
    cg::grid_group grid = cg::this_grid();
    const int tid = threadIdx.x;
    const int w  = tid >> 6, ln = tid & 63;
    const int lr = ln & 15, lg = ln >> 4;
    const int b = blockIdx.x & 7;            // batch -> XCD
    const int local = blockIdx.x >> 3;       // 0..31
    const int tok0 = b * SS + local * 32;

    __shared__ __align__(16) char smem[129024];
    float* xlds  = (float*)smem;                   // [32][268] f32 (persistent)
    short* ylds  = (short*)(smem + 34304);         // 16KB packed y
    char*  R1    = smem + 34304 + 16384;           // 78336B union region
    float* accP  = (float*)R1;                     // attn merge slots
    float* lsLf  = (float*)(R1 + 67584);           // [8][16]
    short* wldsA = (short*)(R1 + 68096);           // [8][640]
    float* outw  = (float*)R1;                     // [32][268] f32 (wcffn)
    char*  qls   = R1 + 34304;                     // [32][256] bf16 swizzled
    char*  hls   = R1 + 34304 + 16384;             // [32][256] bf16 swizzled
    float* fout  = (float*)(R1 + 34304);           // [32][256] f32 overlay

    const float scale = 0.17677669529663687f;      // 1/sqrt(32)

    for (int lyr = 0; lyr < LL; ++lyr) {
        const short* PQr = (lyr & 1) ? PQ1 : PQ0;
        const short* PTr = (lyr & 1) ? PT1 : PT0;
        short* PQw = (lyr & 1) ? PQ0 : PQ1;
        short* PTw = (lyr & 1) ? PT0 : PT1;
        const short* pq = PQr + (size_t)b * SS * EE;
        const short* pt = PTr + (size_t)b * SS * EE;
        const short* WcPl = WcP + (size_t)lyr * EE * EE;
        const short* W1Pl = W1P + (size_t)lyr * FF * NQQ;
        const short* W2Pl = W2P + (size_t)lyr * EE * FF;
        const float* bcl  = bc  + lyr * EE;
        const float* g1l  = g1  + lyr * EE;
        const float* bn1l = bn1 + lyr * EE;
        const float* tfl  = theta_ffn + lyr * NQQ;
        const float* b1l  = b1  + lyr * FF;
        const float* b2l  = b2  + lyr * EE;
        const float* g2l  = g2  + lyr * EE;
        const float* bn2l = bn2 + lyr * EE;

        // ================= ATTN PHASE (waves 0..7) =================
        f32x4 acc[16];
        float ls[4];
        const int qg = w >> 2, wk = w & 3;
        if (w < 8) {
            const int qt = local * 2 + qg;
            short8 qf[8];
            #pragma unroll
            for (int kg = 0; kg < 8; ++kg)
                qf[kg] = *(const short8*)FRAG(pq, qt*8 + kg, 1, 0, ln);
            #pragma unroll
            for (int i = 0; i < 16; ++i) acc[i] = f32x4{0.f, 0.f, 0.f, 0.f};
            ls[0] = ls[1] = ls[2] = ls[3] = 0.f;
            short* wl = wldsA + w * 640;

            for (int i = 0; i < 8; ++i) {
                const int kt = wk + 4 * i;
                short8 sb0[8], sb1[8];
                #pragma unroll
                for (int kg = 0; kg < 8; ++kg) {
                    sb0[kg] = *(const short8*)FRAG(pq, (2*kt)*8   + kg, 1, 0, ln);
                    sb1[kg] = *(const short8*)FRAG(pq, (2*kt+1)*8 + kg, 1, 0, ln);
                }
                f32x4 s0a = {0.f,0.f,0.f,0.f}, s0b = {0.f,0.f,0.f,0.f};
                f32x4 s1a = {0.f,0.f,0.f,0.f}, s1b = {0.f,0.f,0.f,0.f};
                #pragma unroll
                for (int kg = 0; kg < 4; ++kg) {
                    s0a = mfma16(qf[kg], sb0[kg], s0a);
                    s1a = mfma16(qf[kg], sb1[kg], s1a);
                }
                #pragma unroll
                for (int kg = 4; kg < 8; ++kg) {
                    s0b = mfma16(qf[kg], sb0[kg], s0b);
                    s1b = mfma16(qf[kg], sb1[kg], s1b);
                }
                short8 pvb0[8];
                #pragma unroll
                for (int nt = 0; nt < 8; ++nt)
                    pvb0[nt] = *(const short8*)FRAG(pt, nt, 32, kt, ln);

                #pragma unroll
                for (int r = 0; r < 4; ++r) {
                    float p0 = __expf((s0a[r] + s0b[r]) * scale);
                    float p1 = __expf((s1a[r] + s1b[r]) * scale);
                    ls[r] += p0 + p1;
                    int qq = lg * 4 + r;
                    wl[qq * 40 + lr]      = f2bf(p0);
                    wl[qq * 40 + 16 + lr] = f2bf(p1);
                }
                short8 pa = *(const short8*)(wl + lr * 40 + lg * 8);
                short8 pvb1[8];
                #pragma unroll
                for (int nt = 0; nt < 8; ++nt)
                    pvb1[nt] = *(const short8*)FRAG(pt, 8 + nt, 32, kt, ln);
                #pragma unroll
                for (int nt = 0; nt < 8; ++nt)
                    acc[nt] = mfma16(pa, pvb0[nt], acc[nt]);
                #pragma unroll
                for (int nt = 0; nt < 8; ++nt)
                    acc[8 + nt] = mfma16(pa, pvb1[nt], acc[8 + nt]);
            }

            #pragma unroll
            for (int r = 0; r < 4; ++r) {
                ls[r] += __shfl_xor(ls[r], 1);
                ls[r] += __shfl_xor(ls[r], 2);
                ls[r] += __shfl_xor(ls[r], 4);
                ls[r] += __shfl_xor(ls[r], 8);
            }
            if (lr == 0) {
                #pragma unroll
                for (int r = 0; r < 4; ++r)
                    lsLf[w * 16 + lg * 4 + r] = ls[r];
            }
            if (wk >= 2) {
                #pragma unroll
                for (int nt = 0; nt < 16; ++nt)
                    #pragma unroll
                    for (int r = 0; r < 4; ++r)
                        ACCP(qg, wk - 2, lg*4 + r, nt*16 + lr) = acc[nt][r];
            }
        }
        __syncthreads();
        if (w < 8 && wk < 2) {
            #pragma unroll
            for (int nt = 0; nt < 16; ++nt)
                #pragma unroll
                for (int r = 0; r < 4; ++r)
                    ACCP(qg, wk, lg*4 + r, nt*16 + lr) += acc[nt][r];
        }
        __syncthreads();
        if (tid < 512) {
            const int qg2 = tid >> 8, rest = tid & 255;
            const int q = rest >> 4, c = rest & 15;
            float L = lsLf[(qg2*4 + 0)*16 + q] + lsLf[(qg2*4 + 1)*16 + q]
                    + lsLf[(qg2*4 + 2)*16 + q] + lsLf[(qg2*4 + 3)*16 + q];
            float inv = 1.0f / L;
            short ov[16];
            #pragma unroll
            for (int j = 0; j < 4; ++j) {
                float4 a  = *(const float4*)&ACCP(qg2, 0, q, c*16 + j*4);
                float4 bb = *(const float4*)&ACCP(qg2, 1, q, c*16 + j*4);
                ov[j*4 + 0] = f2bf((a.x + bb.x) * inv);
                ov[j*4 + 1] = f2bf((a.y + bb.y) * inv);
                ov[j*4 + 2] = f2bf((a.z + bb.z) * inv);
                ov[j*4 + 3] = f2bf((a.w + bb.w) * inv);
            }
            int kgo = c >> 1, lgo = (c & 1) * 2;
            *(short8*)(ylds + (((qg2*8 + kgo)*64) + lgo*16 + q)*8)     = *(const short8*)&ov[0];
            *(short8*)(ylds + (((qg2*8 + kgo)*64) + (lgo+1)*16 + q)*8) = *(const short8*)&ov[8];
        }
        __syncthreads();

        // ================= WCFFN PHASE (16 waves) =================
        // Phase A: wc GEMM from ylds
        {
            const int wg = w >> 3, wn8 = w & 7;
            short8 af[8];
            #pragma unroll
            for (int kg = 0; kg < 8; ++kg)
                af[kg] = *(const short8*)(ylds + (((wg*8 + kg)*64) + ln)*8);
            f32x4 a[2];
            a[0] = f32x4{0.f,0.f,0.f,0.f};
            a[1] = f32x4{0.f,0.f,0.f,0.f};
            #pragma unroll
            for (int nt = 0; nt < 2; ++nt) {
                #pragma unroll
                for (int kg = 0; kg < 8; ++kg) {
                    short8 bv = *(const short8*)FRAG(WcPl, wn8*2 + nt, 8, kg, ln);
                    a[nt] = mfma16(af[kg], bv, a[nt]);
                }
            }
            #pragma unroll
            for (int nt = 0; nt < 2; ++nt) {
                int e = wn8 * 32 + nt * 16 + lr;
                float bce = bcl[e];
                #pragma unroll
                for (int r = 0; r < 4; ++r)
                    outw[(wg*16 + lg*4 + r) * 268 + e] = a[nt][r] + bce;
            }
        }
        __syncthreads();

        // Phase A epilogue: residual + LN1 -> x1 (outw); stage qls
        #pragma unroll
        for (int j = 0; j < 2; ++j) {
            int q = w * 2 + j;
            float4 v = *(float4*)&outw[q * 268 + ln * 4];
            float4 xv;
            if (lyr == 0)
                xv = *(const float4*)(x + (size_t)(tok0 + q) * EE + ln * 4);
            else
                xv = *(const float4*)&xlds[q * 268 + ln * 4];
            v.x += xv.x; v.y += xv.y; v.z += xv.z; v.w += xv.w;
            float s = v.x + v.y + v.z + v.w;
            for (int off = 32; off > 0; off >>= 1) s += __shfl_xor(s, off);
            float mean = s * (1.0f / EE);
            float4 d;
            d.x = v.x - mean; d.y = v.y - mean; d.z = v.z - mean; d.w = v.w - mean;
            float s2 = d.x*d.x + d.y*d.y + d.z*d.z + d.w*d.w;
            for (int off = 32; off > 0; off >>= 1) s2 += __shfl_xor(s2, off);
            float inv = rsqrtf(s2 * (1.0f / EE) + 1e-5f);
            float4 gv  = *(const float4*)(g1l  + ln * 4);
            float4 bnv = *(const float4*)(bn1l + ln * 4);
            float4 o;
            o.x = d.x * inv * gv.x + bnv.x;
            o.y = d.y * inv * gv.y + bnv.y;
            o.z = d.z * inv * gv.z + bnv.z;
            o.w = d.w * inv * gv.w + bnv.w;
            *(float4*)&outw[q * 268 + ln * 4] = o;      // x1
            float4 tv = *(const float4*)(tfl + ln * 4);
            float q0 = __cosf(o.x) * __cosf(tv.x);
            float q1 = __cosf(o.y) * __cosf(tv.y);
            float q2 = __cosf(o.z) * __cosf(tv.z);
            float q3 = __cosf(o.w) * __cosf(tv.w);
            int byte = (q * 512 + ln * 8) ^ ((q & 7) << 4);
            *(unsigned*)(qls + byte) =
                (unsigned)(unsigned short)f2bf(q0) | ((unsigned)(unsigned short)f2bf(q1) << 16);
            *(unsigned*)(qls + byte + 4) =
                (unsigned)(unsigned short)f2bf(q2) | ((unsigned)(unsigned short)f2bf(q3) << 16);
        }
        __syncthreads();

        // Phase B: FFN f-chunked
        f32x4 acc2[2];
        acc2[0] = f32x4{0.f,0.f,0.f,0.f};
        acc2[1] = f32x4{0.f,0.f,0.f,0.f};
        for (int fc = 0; fc < 4; ++fc) {
            f32x4 acc1[2];
            acc1[0] = f32x4{0.f,0.f,0.f,0.f};
            acc1[1] = f32x4{0.f,0.f,0.f,0.f};
            #pragma unroll
            for (int kg = 0; kg < 8; ++kg) {
                int ca = (kg*32 + lg*8) * 2;
                short8 a0 = *(const short8*)(qls + ((lr*512      + ca) ^ ((lr & 7) << 4)));
                short8 a1 = *(const short8*)(qls + (((16+lr)*512 + ca) ^ ((lr & 7) << 4)));
                short8 bv = *(const short8*)FRAG(W1Pl, fc*16 + w, 8, kg, ln);
                acc1[0] = mfma16(a0, bv, acc1[0]);
                acc1[1] = mfma16(a1, bv, acc1[1]);
            }
            {
                int fcol = w * 16 + lr;
                float bb = b1l[fc * 256 + fcol];
                #pragma unroll
                for (int mt = 0; mt < 2; ++mt) {
                    #pragma unroll
                    for (int r = 0; r < 4; ++r) {
                        int tq = mt * 16 + lg * 4 + r;
                        float hv = fmaxf(acc1[mt][r] + bb, 0.0f);
                        int byte = (tq * 512 + fcol * 2) ^ ((tq & 7) << 4);
                        *(short*)(hls + byte) = f2bf(hv);
                    }
                }
            }
            __syncthreads();
            #pragma unroll
            for (int k8 = 0; k8 < 8; ++k8) {
                int ca = (k8*32 + lg*8) * 2;
                short8 h0 = *(const short8*)(hls + ((lr*512      + ca) ^ ((lr & 7) << 4)));
                short8 h1 = *(const short8*)(hls + (((16+lr)*512 + ca) ^ ((lr & 7) << 4)));
                short8 bv = *(const short8*)FRAG(W2Pl, w, 32, fc*8 + k8, ln);
                acc2[0] = mfma16(h0, bv, acc2[0]);
                acc2[1] = mfma16(h1, bv, acc2[1]);
            }
            __syncthreads();
        }

        {   // fout overlay (qls+hls free now)
            int e = w * 16 + lr;
            float b2e = b2l[e];
            #pragma unroll
            for (int mt = 0; mt < 2; ++mt)
                #pragma unroll
                for (int r = 0; r < 4; ++r)
                    fout[(mt*16 + lg*4 + r) * 256 + e] = acc2[mt][r] + b2e;
        }
        __syncthreads();

        // Phase B epilogue: residual(x1) + LN2 -> x2 (xlds)
        #pragma unroll
        for (int j = 0; j < 2; ++j) {
            int q = w * 2 + j;
            float4 v  = *(float4*)&fout[q * 256 + ln * 4];
            float4 x1 = *(float4*)&outw[q * 268 + ln * 4];
            v.x += x1.x; v.y += x1.y; v.z += x1.z; v.w += x1.w;
            float s = v.x + v.y + v.z + v.w;
            for (int off = 32; off > 0; off >>= 1) s += __shfl_xor(s, off);
            float mean = s * (1.0f / EE);
            float4 d;
            d.x = v.x - mean; d.y = v.y - mean; d.z = v.z - mean; d.w = v.w - mean;
            float s2 = d.x*d.x + d.y*d.y + d.z*d.z + d.w*d.w;
            for (int off = 32; off > 0; off >>= 1) s2 += __shfl_xor(s2, off);
            float inv = rsqrtf(s2 * (1.0f / EE) + 1e-5f);
            float4 gv  = *(const float4*)(g2l  + ln * 4);
            float4 bnv = *(const float4*)(bn2l + ln * 4);
            float4 o;
            o.x = d.x * inv * gv.x + bnv.x;
            o.y = d.y * inv * gv.y + bnv.y;
            o.z = d.z * inv * gv.z + bnv.z;
            o.w = d.w * inv * gv.w + bnv.w;
            *(float4*)&xlds[q * 268 + ln * 4] = o;      // x2 persists in LDS
        }
        __syncthreads();

        if (lyr + 1 < LL) {
            // Phase C: next-layer qproj from xlds -> ping-pong PQ/PT
            if (tid < 256) {
                int sl = tid >> 3, h = tid & 7;
                int bs = tok0 + sl;
                qproj_row(&xlds[sl * 268], theta_attn + (size_t)(lyr+1)*HH*DKK + h*DKK,
                          bs >> 10, bs & (SS - 1), h, PQw, PTw);
            }
            __threadfence();
            grid.sync();
        } else {
            // Phase C': head partial sums from xlds
            if (tid < 256) {
                float a = 0.0f;
                #pragma unroll 8
                for (int r = 0; r < 32; ++r)
                    a += xlds[r * 268 + tid];
                hpart[(size_t)(b * 32 + local) * EE + tid] = a;
            }
        }
    }
}

// ---------------------------------------------------------------------------
// Kernel 3: head reduce + classifier. grid = B blocks, 256 threads.
// ---------------------------------------------------------------------------
__global__ __launch_bounds__(256) void k_head2(const float* __restrict__ hpart,
                                               const float* __restrict__ Wcls,
                                               const float* __restrict__ bcls,
                                               float* __restrict__ out) {
    int b = blockIdx.x;
    int t = threadIdx.x;
    __shared__ float xm[EE];
    float acc = 0.0f;
    #pragma unroll 8
    for (int j = 0; j < 32; ++j)
        acc += hpart[(size_t)(b * 32 + j) * EE + t];
    xm[t] = acc * (1.0f / (float)SS);
    __syncthreads();
    if (t < CC) {
        float a = bcls[t];
        #pragma unroll 8
        for (int e = 0; e < EE; ++e) a += xm[e] * Wcls[e * CC + t];
        out[b * CC + t] = a;
    }
}

// ---------------------------------------------------------------------------
extern "C" void kernel_launch(void* const* d_in, const int* in_sizes, int n_in,
                              void* d_out, int out_size, void* d_ws, size_t ws_size,
                              hipStream_t stream) {
    (void)in_sizes; (void)n_in; (void)out_size; (void)ws_size;
    const int*   tokens     = (const int*)d_in[0];
    const float* emb        = (const float*)d_in[1];
    const float* theta_attn = (const float*)d_in[2];
    const float* Wc         = (const float*)d_in[3];
    const float* bc         = (const float*)d_in[4];
    const float* g1         = (const float*)d_in[5];
    const float* bn1        = (const float*)d_in[6];
    const float* theta_ffn  = (const float*)d_in[7];
    const float* W1         = (const float*)d_in[8];
    const float* b1         = (const float*)d_in[9];
    const float* W2         = (const float*)d_in[10];
    const float* b2         = (const float*)d_in[11];
    const float* g2         = (const float*)d_in[12];
    const float* bn2        = (const float*)d_in[13];
    const float* Wcls       = (const float*)d_in[14];
    const float* bcls       = (const float*)d_in[15];
    float* out = (float*)d_out;

    const size_t nTok = (size_t)BB * SS * EE;     // 2M
    float* x     = (float*)d_ws;                  // 8 MB
    short* PQ0   = (short*)(x + nTok);            // 4 MB
    short* PT0   = PQ0 + nTok;                    // 4 MB
    short* W1P   = PT0 + nTok;                    // 2 MB
    short* W2P   = W1P + (size_t)LL * FF * NQQ;   // 2 MB
    short* WcP   = W2P + (size_t)LL * EE * FF;    // 0.5 MB
    float* hpart = (float*)(WcP + (size_t)LL * EE * EE);  // 256 KB
    short* PQ1   = (short*)(hpart + (size_t)BB * 32 * EE); // 4 MB
    short* PT1   = PQ1 + nTok;                    // 4 MB  (total ~28.75 MB)

    k_prep<<<2304 + 512, 256, 0, stream>>>(
        W1, W2, Wc, W1P, W2P, WcP, tokens, emb, theta_attn, x, PQ0, PT0);

    void* kargs[] = {
        (void*)&PQ0, (void*)&PT0, (void*)&PQ1, (void*)&PT1,
        (void*)&WcP, (void*)&W1P, (void*)&W2P,
        (void*)&bc, (void*)&g1, (void*)&bn1, (void*)&theta_ffn,
        (void*)&b1, (void*)&b2, (void*)&g2, (void*)&bn2,
        (void*)&theta_attn, (void*)&x, (void*)&hpart
    };
    hipLaunchCooperativeKernel((const void*)k_layers, dim3(256), dim3(1024),
                               kargs, 0, stream);

    k_head2<<<BB, 256, 0, stream>>>(hpart, Wcls, bcls, out);
}

// Round 18
// 248.522 us; speedup vs baseline: 4.4692x; 4.4692x over previous
//
#include <hip/hip_runtime.h>
#include <hip/hip_bf16.h>
#include <math.h>

#define BB 8
#define SS 1024
#define EE 256
#define HH 8
#define DKK 32
#define LL 4
#define FF 1024
#define NQQ 256
#define CC 10

typedef __attribute__((ext_vector_type(8))) short short8;
typedef __attribute__((ext_vector_type(4))) short s16x4;
typedef __attribute__((ext_vector_type(4))) float f32x4;

static __device__ __forceinline__ f32x4 mfma16(short8 a, short8 b, f32x4 c) {
    return __builtin_amdgcn_mfma_f32_16x16x32_bf16(a, b, c, 0, 0, 0);
}
static __device__ __forceinline__ short f2bf(float f) {
    __hip_bfloat16 h = __float2bfloat16(f);
    return *reinterpret_cast<short*>(&h);
}

// Fragment-packed layout: P[(tile*KG + kg)*64 + lane] (short8 units).
#define FRAG(P, tile, KG, kg, l) ((P) + (((size_t)((tile)*(KG) + (kg)))*64 + (l))*8)

// ---------------------------------------------------------------------------
// qproj from an LDS row (stride-268 f32): thread handles one (s,h).
// ---------------------------------------------------------------------------
static __device__ __forceinline__ void qproj_row(
        const float* __restrict__ xrow,
        const float* __restrict__ th,
        int b, int s, int h,
        short* __restrict__ PQ, short* __restrict__ PT) {
    float v[DKK];
    float cum = __cosf(xrow[h * DKK + 0] + th[0]);
    float prod1 = 1.0f;
    #pragma unroll
    for (int j = 1; j < DKK; ++j) {
        float c = __cosf(xrow[h * DKK + j] + th[j]);
        cum *= c;
        prod1 *= c;
        v[j] = cum;
    }
    v[0] = prod1;
    short* pq = PQ + (size_t)b * SS * EE;
    int stile = s >> 4, lr = s & 15;
    #pragma unroll
    for (int lg = 0; lg < 4; ++lg) {
        short8 u;
        #pragma unroll
        for (int j = 0; j < 8; ++j) u[j] = f2bf(v[lg*8 + j]);
        *(short8*)FRAG(pq, stile*8 + h, 1, 0, lg*16 + lr) = u;
    }
    short* pt = PT + (size_t)b * SS * EE;
    int kt = s >> 5, lgs = (s >> 3) & 3, j0 = s & 7;
    #pragma unroll
    for (int j = 0; j < DKK; ++j) {
        int e = h * DKK + j;
        FRAG(pt, e >> 4, 32, kt, lgs*16 + (e & 15))[j0] = f2bf(v[j]);
    }
}

// ---------------------------------------------------------------------------
// Kernel 1: MERGED prep. bid<2304: weight transpose/pack. bid>=2304: embed +
// pos-encoding + layer-0 qproj (16 tokens/block, 256 thr).
// ---------------------------------------------------------------------------
__global__ __launch_bounds__(256) void k_prep(
        const float* __restrict__ W1, const float* __restrict__ W2,
        const float* __restrict__ Wc,
        short* __restrict__ W1P, short* __restrict__ W2P, short* __restrict__ WcP,
        const int* __restrict__ tokens, const float* __restrict__ emb,
        const float* __restrict__ theta_q,
        float* __restrict__ x, short* __restrict__ PQ, short* __restrict__ PT) {
    __shared__ float shmem[16 * 268];
    const int t = threadIdx.x;
    if (blockIdx.x < 2304) {
        // ---- trall ----
        int bid = blockIdx.x;
        int lyr = bid / 576, rem = bid % 576;
        const float* in; short* out; int R, C, tile;
        if (rem < 256)      { in = W1 + (size_t)lyr*NQQ*FF; out = W1P + (size_t)lyr*FF*NQQ; R = NQQ; C = FF;  tile = rem; }
        else if (rem < 512) { in = W2 + (size_t)lyr*FF*EE;  out = W2P + (size_t)lyr*EE*FF;  R = FF;  C = EE;  tile = rem - 256; }
        else                { in = Wc + (size_t)lyr*EE*EE;  out = WcP + (size_t)lyr*EE*EE;  R = EE;  C = EE;  tile = rem - 512; }
        const int KG = R >> 5;
        int tiles_c = C >> 5;
        int tc = tile % tiles_c, tr = tile / tiles_c;
        float (*tl)[33] = (float(*)[33])shmem;
        int rr = t >> 5, cc = t & 31;
        #pragma unroll
        for (int i = 0; i < 4; ++i)
            tl[rr + i*8][cc] = in[(size_t)(tr*32 + rr + i*8) * C + tc*32 + cc];
        __syncthreads();
        int ro = t >> 3, co = (t & 7) * 4;
        int n = tc*32 + ro;
        int k = tr*32 + co;
        int ntile = n >> 4, lr = n & 15;
        int kg = k >> 5, lg = (k & 31) >> 3, j0 = k & 7;
        s16x4 v;
        v[0] = f2bf(tl[co + 0][ro]);
        v[1] = f2bf(tl[co + 1][ro]);
        v[2] = f2bf(tl[co + 2][ro]);
        v[3] = f2bf(tl[co + 3][ro]);
        *(s16x4*)(FRAG(out, ntile, KG, kg, lg*16 + lr) + j0) = v;
    } else {
        // ---- embed + qproj(layer 0), 16 tokens ----
        int blk = blockIdx.x - 2304;
        int bsw = blk & 7, local = blk >> 3;        // batch -> XCD
        int tok0 = bsw * SS + local * 16;
        {
            int r = t >> 4, c0 = (t & 15) * 16;
            int bs = tok0 + r;
            int s  = bs & (SS - 1);
            int tok = tokens[bs];
            const float* er = emb + (size_t)tok * EE + c0;
            float vals[16];
            #pragma unroll
            for (int i = 0; i < 16; ++i) {
                int col = c0 + i;
                int i2 = col >> 1;
                float div = __expf(-(float)(2 * i2) * (logf(10000.0f) / (float)EE));
                float ang = (float)s * div;
                float pe = (col & 1) ? __cosf(ang) : __sinf(ang);
                vals[i] = er[i] + pe;
                shmem[r * 268 + col] = vals[i];
            }
            float* xg = x + (size_t)bs * EE + c0;
            #pragma unroll
            for (int i4 = 0; i4 < 4; ++i4)
                *(float4*)(xg + i4 * 4) = *(const float4*)&vals[i4 * 4];
        }
        __syncthreads();
        if (t < 128) {
            int sl = t >> 3, h = t & 7;
            int bs = tok0 + sl;
            qproj_row(&shmem[sl * 268], theta_q + h * DKK,
                      bs >> 10, bs & (SS - 1), h, PQ, PT);
        }
    }
}

// ---------------------------------------------------------------------------
// Kernel 3: attention — R12 structure (best known): 4 waves, KV-split,
// 2-slot additive merge, no online softmax, XCD-swizzled.
// ---------------------------------------------------------------------------
__global__ __launch_bounds__(256) void k_attn7(const short* __restrict__ PQ,
                                               const short* __restrict__ PT,
                                               short* __restrict__ YP) {
    const int b   = blockIdx.x & 7;       // batch -> XCD
    const int qt  = blockIdx.x >> 3;
    const int tid = threadIdx.x;
    const int w   = tid >> 6;
    const int l   = tid & 63;
    const int lr  = l & 15, lg = l >> 4;
    const short* pq = PQ + (size_t)b * SS * EE;
    const short* pt = PT + (size_t)b * SS * EE;

    __shared__ float accP[2][16][264];
    __shared__ float lsL[4][16];
    __shared__ short wlds[4][16 * 40];

    short8 qf[8];
    #pragma unroll
    for (int kg = 0; kg < 8; ++kg)
        qf[kg] = *(const short8*)FRAG(pq, qt*8 + kg, 1, 0, l);

    f32x4 acc[16];
    #pragma unroll
    for (int i = 0; i < 16; ++i) acc[i] = f32x4{0.f, 0.f, 0.f, 0.f};
    float ls[4] = {0.f, 0.f, 0.f, 0.f};
    const float scale = 0.17677669529663687f;
    short* wl = wlds[w];

    for (int i = 0; i < 8; ++i) {
        const int kt = w + 4 * i;
        short8 sb0[8], sb1[8];
        #pragma unroll
        for (int kg = 0; kg < 8; ++kg) {
            sb0[kg] = *(const short8*)FRAG(pq, (2*kt)*8   + kg, 1, 0, l);
            sb1[kg] = *(const short8*)FRAG(pq, (2*kt+1)*8 + kg, 1, 0, l);
        }
        f32x4 s0a = {0.f,0.f,0.f,0.f}, s0b = {0.f,0.f,0.f,0.f};
        f32x4 s1a = {0.f,0.f,0.f,0.f}, s1b = {0.f,0.f,0.f,0.f};
        #pragma unroll
        for (int kg = 0; kg < 4; ++kg) {
            s0a = mfma16(qf[kg], sb0[kg], s0a);
            s1a = mfma16(qf[kg], sb1[kg], s1a);
        }
        #pragma unroll
        for (int kg = 4; kg < 8; ++kg) {
            s0b = mfma16(qf[kg], sb0[kg], s0b);
            s1b = mfma16(qf[kg], sb1[kg], s1b);
        }
        short8 pvb0[8];
        #pragma unroll
        for (int nt = 0; nt < 8; ++nt)
            pvb0[nt] = *(const short8*)FRAG(pt, nt, 32, kt, l);

        #pragma unroll
        for (int r = 0; r < 4; ++r) {
            float p0 = __expf((s0a[r] + s0b[r]) * scale);
            float p1 = __expf((s1a[r] + s1b[r]) * scale);
            ls[r] += p0 + p1;
            int q = lg * 4 + r;
            wl[q * 40 + lr]      = f2bf(p0);
            wl[q * 40 + 16 + lr] = f2bf(p1);
        }
        short8 pa = *(const short8*)(wl + lr * 40 + lg * 8);
        short8 pvb1[8];
        #pragma unroll
        for (int nt = 0; nt < 8; ++nt)
            pvb1[nt] = *(const short8*)FRAG(pt, 8 + nt, 32, kt, l);
        #pragma unroll
        for (int nt = 0; nt < 8; ++nt)
            acc[nt] = mfma16(pa, pvb0[nt], acc[nt]);
        #pragma unroll
        for (int nt = 0; nt < 8; ++nt)
            acc[8 + nt] = mfma16(pa, pvb1[nt], acc[8 + nt]);
    }

    #pragma unroll
    for (int r = 0; r < 4; ++r) {
        ls[r] += __shfl_xor(ls[r], 1);
        ls[r] += __shfl_xor(ls[r], 2);
        ls[r] += __shfl_xor(ls[r], 4);
        ls[r] += __shfl_xor(ls[r], 8);
    }
    if (lr == 0) {
        #pragma unroll
        for (int r = 0; r < 4; ++r)
            lsL[w][lg * 4 + r] = ls[r];
    }

    if (w >= 2) {
        #pragma unroll
        for (int nt = 0; nt < 16; ++nt)
            #pragma unroll
            for (int r = 0; r < 4; ++r)
                accP[w - 2][lg * 4 + r][nt * 16 + lr] = acc[nt][r];
    }
    __syncthreads();
    if (w < 2) {
        #pragma unroll
        for (int nt = 0; nt < 16; ++nt)
            #pragma unroll
            for (int r = 0; r < 4; ++r)
                accP[w][lg * 4 + r][nt * 16 + lr] += acc[nt][r];
    }
    __syncthreads();

    const int q = tid >> 4, c = tid & 15;
    float L = lsL[0][q] + lsL[1][q] + lsL[2][q] + lsL[3][q];
    float inv = 1.0f / L;
    short ov[16];
    #pragma unroll
    for (int j = 0; j < 4; ++j) {
        float4 a  = *(const float4*)&accP[0][q][c * 16 + j * 4];
        float4 bb = *(const float4*)&accP[1][q][c * 16 + j * 4];
        ov[j*4 + 0] = f2bf((a.x + bb.x) * inv);
        ov[j*4 + 1] = f2bf((a.y + bb.y) * inv);
        ov[j*4 + 2] = f2bf((a.z + bb.z) * inv);
        ov[j*4 + 3] = f2bf((a.w + bb.w) * inv);
    }
    short* yb = YP + (size_t)b * SS * EE;
    int kgo = c >> 1, lgo = (c & 1) * 2;
    *(short8*)FRAG(yb, qt*8 + kgo, 1, 0, lgo*16 + q)     = *(const short8*)&ov[0];
    *(short8*)FRAG(yb, qt*8 + kgo, 1, 0, (lgo+1)*16 + q) = *(const short8*)&ov[8];
}

// ---------------------------------------------------------------------------
// Kernel 4: FUSED wc+LN1 + FFN+LN2 + next-layer qproj / head-partials.
// 1024 threads / 16 waves per 32-token block (R16 best-known).
// ---------------------------------------------------------------------------
__global__ __launch_bounds__(1024) void k_wcffnq(
        const short* __restrict__ YP, const short* __restrict__ WcP,
        const float* __restrict__ bc, const float* __restrict__ g1,
        const float* __restrict__ bn1,
        const float* __restrict__ tf, const short* __restrict__ W1P,
        const float* __restrict__ b1, const short* __restrict__ W2P,
        const float* __restrict__ b2, const float* __restrict__ g2,
        const float* __restrict__ bn2,
        float* __restrict__ x,
        const float* __restrict__ theta_q, short* __restrict__ PQ,
        short* __restrict__ PT, float* __restrict__ hpart, int has_next) {
    const int t = threadIdx.x, w = t >> 6, l = t & 63;   // w: 0..15
    const int lr = l & 15, lg = l >> 4;
    const int b = blockIdx.x & 7;            // batch -> XCD
    const int local = blockIdx.x >> 3;       // 0..31
    const int tok0 = b * SS + local * 32;
    const int qt0 = local * 2;

    __shared__ __align__(16) char smem[34304 + 16384 + 16384];
    float* outw = (float*)smem;                    // [32][268] f32
    char*  qls  = smem + 34304;                    // [32][256] bf16 swizzled
    char*  hls  = smem + 34304 + 16384;            // [32][256] bf16 swizzled
    float* fout = (float*)(smem + 34304);          // [32][256] f32 overlay

    const short* yb = YP + (size_t)b * SS * EE;

    // ---------- Phase A: wc GEMM ----------
    {
        const int wg = w >> 3, wn8 = w & 7;
        short8 af[8];
        #pragma unroll
        for (int kg = 0; kg < 8; ++kg)
            af[kg] = *(const short8*)FRAG(yb, (qt0 + wg)*8 + kg, 1, 0, l);
        f32x4 acc[2];
        acc[0] = f32x4{0.f,0.f,0.f,0.f};
        acc[1] = f32x4{0.f,0.f,0.f,0.f};
        #pragma unroll
        for (int nt = 0; nt < 2; ++nt) {
            #pragma unroll
            for (int kg = 0; kg < 8; ++kg) {
                short8 bv = *(const short8*)FRAG(WcP, wn8*2 + nt, 8, kg, l);
                acc[nt] = mfma16(af[kg], bv, acc[nt]);
            }
        }
        #pragma unroll
        for (int nt = 0; nt < 2; ++nt) {
            int e = wn8 * 32 + nt * 16 + lr;
            float bce = bc[e];
            #pragma unroll
            for (int r = 0; r < 4; ++r)
                outw[(wg*16 + lg*4 + r) * 268 + e] = acc[nt][r] + bce;
        }
    }
    __syncthreads();

    // ---------- Phase A epilogue: residual+LN1 -> x1; stage q into qls ------
    #pragma unroll
    for (int j = 0; j < 2; ++j) {
        int q = w * 2 + j;
        float4 v  = *(float4*)&outw[q * 268 + l * 4];
        float4 xv = *(const float4*)(x + (size_t)(tok0 + q) * EE + l * 4);
        v.x += xv.x; v.y += xv.y; v.z += xv.z; v.w += xv.w;
        float s = v.x + v.y + v.z + v.w;
        for (int off = 32; off > 0; off >>= 1) s += __shfl_xor(s, off);
        float mean = s * (1.0f / EE);
        float4 d;
        d.x = v.x - mean; d.y = v.y - mean; d.z = v.z - mean; d.w = v.w - mean;
        float s2 = d.x*d.x + d.y*d.y + d.z*d.z + d.w*d.w;
        for (int off = 32; off > 0; off >>= 1) s2 += __shfl_xor(s2, off);
        float inv = rsqrtf(s2 * (1.0f / EE) + 1e-5f);
        float4 gv  = *(const float4*)(g1  + l * 4);
        float4 bnv = *(const float4*)(bn1 + l * 4);
        float4 o;
        o.x = d.x * inv * gv.x + bnv.x;
        o.y = d.y * inv * gv.y + bnv.y;
        o.z = d.z * inv * gv.z + bnv.z;
        o.w = d.w * inv * gv.w + bnv.w;
        *(float4*)&outw[q * 268 + l * 4] = o;
        float4 tv = *(const float4*)(tf + l * 4);
        float q0 = __cosf(o.x) * __cosf(tv.x);
        float q1 = __cosf(o.y) * __cosf(tv.y);
        float q2 = __cosf(o.z) * __cosf(tv.z);
        float q3 = __cosf(o.w) * __cosf(tv.w);
        int byte = (q * 512 + l * 8) ^ ((q & 7) << 4);
        *(unsigned*)(qls + byte) =
            (unsigned)(unsigned short)f2bf(q0) | ((unsigned)(unsigned short)f2bf(q1) << 16);
        *(unsigned*)(qls + byte + 4) =
            (unsigned)(unsigned short)f2bf(q2) | ((unsigned)(unsigned short)f2bf(q3) << 16);
    }
    __syncthreads();

    // ---------- Phase B: FFN (f-chunked) ----------
    f32x4 acc2[2];
    acc2[0] = f32x4{0.f,0.f,0.f,0.f};
    acc2[1] = f32x4{0.f,0.f,0.f,0.f};

    for (int fc = 0; fc < 4; ++fc) {
        f32x4 acc1[2];
        acc1[0] = f32x4{0.f,0.f,0.f,0.f};
        acc1[1] = f32x4{0.f,0.f,0.f,0.f};
        #pragma unroll
        for (int kg = 0; kg < 8; ++kg) {
            int ca = (kg*32 + lg*8) * 2;
            short8 a0 = *(const short8*)(qls + ((lr*512      + ca) ^ ((lr & 7) << 4)));
            short8 a1 = *(const short8*)(qls + (((16+lr)*512 + ca) ^ ((lr & 7) << 4)));
            short8 bv = *(const short8*)FRAG(W1P, fc*16 + w, 8, kg, l);
            acc1[0] = mfma16(a0, bv, acc1[0]);
            acc1[1] = mfma16(a1, bv, acc1[1]);
        }
        {
            int fcol = w * 16 + lr;              // col within 256-f chunk
            float bb = b1[fc * 256 + fcol];
            #pragma unroll
            for (int mt = 0; mt < 2; ++mt) {
                #pragma unroll
                for (int r = 0; r < 4; ++r) {
                    int tq = mt * 16 + lg * 4 + r;
                    float hv = fmaxf(acc1[mt][r] + bb, 0.0f);
                    int byte = (tq * 512 + fcol * 2) ^ ((tq & 7) << 4);
                    *(short*)(hls + byte) = f2bf(hv);
                }
            }
        }
        __syncthreads();
        #pragma unroll
        for (int k8 = 0; k8 < 8; ++k8) {
            int ca = (k8*32 + lg*8) * 2;
            short8 h0 = *(const short8*)(hls + ((lr*512      + ca) ^ ((lr & 7) << 4)));
            short8 h1 = *(const short8*)(hls + (((16+lr)*512 + ca) ^ ((lr & 7) << 4)));
            short8 bv = *(const short8*)FRAG(W2P, w, 32, fc*8 + k8, l);
            acc2[0] = mfma16(h0, bv, acc2[0]);
            acc2[1] = mfma16(h1, bv, acc2[1]);
        }
        __syncthreads();
    }

    {   // fout overlay (qls+hls free now)
        int e = w * 16 + lr;
        float b2e = b2[e];
        #pragma unroll
        for (int mt = 0; mt < 2; ++mt)
            #pragma unroll
            for (int r = 0; r < 4; ++r)
                fout[(mt*16 + lg*4 + r) * 256 + e] = acc2[mt][r] + b2e;
    }
    __syncthreads();

    // ---------- Phase B epilogue: residual(x1)+LN2 -> x2 ----------
    #pragma unroll
    for (int j = 0; j < 2; ++j) {
        int q = w * 2 + j;
        float4 v  = *(float4*)&fout[q * 256 + l * 4];
        float4 x1 = *(float4*)&outw[q * 268 + l * 4];
        v.x += x1.x; v.y += x1.y; v.z += x1.z; v.w += x1.w;
        float s = v.x + v.y + v.z + v.w;
        for (int off = 32; off > 0; off >>= 1) s += __shfl_xor(s, off);
        float mean = s * (1.0f / EE);
        float4 d;
        d.x = v.x - mean; d.y = v.y - mean; d.z = v.z - mean; d.w = v.w - mean;
        float s2 = d.x*d.x + d.y*d.y + d.z*d.z + d.w*d.w;
        for (int off = 32; off > 0; off >>= 1) s2 += __shfl_xor(s2, off);
        float inv = rsqrtf(s2 * (1.0f / EE) + 1e-5f);
        float4 gv  = *(const float4*)(g2  + l * 4);
        float4 bnv = *(const float4*)(bn2 + l * 4);
        float4 o;
        o.x = d.x * inv * gv.x + bnv.x;
        o.y = d.y * inv * gv.y + bnv.y;
        o.z = d.z * inv * gv.z + bnv.z;
        o.w = d.w * inv * gv.w + bnv.w;
        if (has_next)
            *(float4*)(x + (size_t)(tok0 + q) * EE + l * 4) = o;
        *(float4*)&outw[q * 268 + l * 4] = o;
    }
    __syncthreads();

    if (has_next) {
        // ---------- Phase C: next-layer qproj from x2 (LDS) ----------
        if (t < 256) {
            int sl = t >> 3, h = t & 7;
            int bs = tok0 + sl;
            qproj_row(&outw[sl * 268], theta_q + h * DKK,
                      bs >> 10, bs & (SS - 1), h, PQ, PT);
        }
    } else {
        // ---------- Phase C': head partial sums from x2 (LDS) ----------
        if (t < 256) {
            float acc = 0.0f;
            #pragma unroll 8
            for (int r = 0; r < 32; ++r)
                acc += outw[r * 268 + t];
            hpart[(size_t)(b * 32 + local) * EE + t] = acc;
        }
    }
}

// ---------------------------------------------------------------------------
// Kernel 6: head reduce + classifier. grid = B blocks, 256 threads.
// ---------------------------------------------------------------------------
__global__ __launch_bounds__(256) void k_head2(const float* __restrict__ hpart,
                                               const float* __restrict__ Wcls,
                                               const float* __restrict__ bcls,
                                               float* __restrict__ out) {
    int b = blockIdx.x;
    int t = threadIdx.x;
    __shared__ float xm[EE];
    float acc = 0.0f;
    #pragma unroll 8
    for (int j = 0; j < 32; ++j)
        acc += hpart[(size_t)(b * 32 + j) * EE + t];
    xm[t] = acc * (1.0f / (float)SS);
    __syncthreads();
    if (t < CC) {
        float a = bcls[t];
        #pragma unroll 8
        for (int e = 0; e < EE; ++e) a += xm[e] * Wcls[e * CC + t];
        out[b * CC + t] = a;
    }
}

// ---------------------------------------------------------------------------
extern "C" void kernel_launch(void* const* d_in, const int* in_sizes, int n_in,
                              void* d_out, int out_size, void* d_ws, size_t ws_size,
                              hipStream_t stream) {
    (void)in_sizes; (void)n_in; (void)out_size; (void)ws_size;
    const int*   tokens     = (const int*)d_in[0];
    const float* emb        = (const float*)d_in[1];
    const float* theta_attn = (const float*)d_in[2];
    const float* Wc         = (const float*)d_in[3];
    const float* bc         = (const float*)d_in[4];
    const float* g1         = (const float*)d_in[5];
    const float* bn1        = (const float*)d_in[6];
    const float* theta_ffn  = (const float*)d_in[7];
    const float* W1         = (const float*)d_in[8];
    const float* b1         = (const float*)d_in[9];
    const float* W2         = (const float*)d_in[10];
    const float* b2         = (const float*)d_in[11];
    const float* g2         = (const float*)d_in[12];
    const float* bn2        = (const float*)d_in[13];
    const float* Wcls       = (const float*)d_in[14];
    const float* bcls       = (const float*)d_in[15];
    float* out = (float*)d_out;

    const size_t nTok = (size_t)BB * SS * EE;     // 2M
    float* x     = (float*)d_ws;                  // 8 MB
    short* PQ    = (short*)(x + nTok);            // 4 MB
    short* PT    = PQ  + nTok;                    // 4 MB
    short* YP    = PT  + nTok;                    // 4 MB
    short* W1P   = YP  + nTok;                    // 2 MB
    short* W2P   = W1P + (size_t)LL * FF * NQQ;   // 2 MB
    short* WcP   = W2P + (size_t)LL * EE * FF;    // 0.5 MB
    float* hpart = (float*)(WcP + (size_t)LL * EE * EE);  // 256 KB

    k_prep<<<2304 + 512, 256, 0, stream>>>(
        W1, W2, Wc, W1P, W2P, WcP, tokens, emb, theta_attn, x, PQ, PT);

    for (int l = 0; l < LL; ++l) {
        int has_next = (l + 1 < LL) ? 1 : 0;
        const float* thq = theta_attn + (size_t)(has_next ? l + 1 : 0) * HH * DKK;
        k_attn7<<<BB * 64, 256, 0, stream>>>(PQ, PT, YP);
        k_wcffnq<<<(BB * SS) / 32, 1024, 0, stream>>>(
            YP, WcP + (size_t)l * EE * EE, bc + (size_t)l * EE,
            g1 + (size_t)l * EE, bn1 + (size_t)l * EE,
            theta_ffn + (size_t)l * NQQ,
            W1P + (size_t)l * FF * NQQ, b1 + (size_t)l * FF,
            W2P + (size_t)l * EE * FF, b2 + (size_t)l * EE,
            g2 + (size_t)l * EE, bn2 + (size_t)l * EE,
            x, thq, PQ, PT, hpart, has_next);
    }

    k_head2<<<BB, 256, 0, stream>>>(hpart, Wcls, bcls, out);
}

// Round 19
// 233.645 us; speedup vs baseline: 4.7538x; 1.0637x over previous
//
#include <hip/hip_runtime.h>
#include <hip/hip_bf16.h>
#include <math.h>

#define BB 8
#define SS 1024
#define EE 256
#define HH 8
#define DKK 32
#define LL 4
#define FF 1024
#define NQQ 256
#define CC 10

typedef __attribute__((ext_vector_type(8))) short short8;
typedef __attribute__((ext_vector_type(4))) short s16x4;
typedef __attribute__((ext_vector_type(4))) float f32x4;

static __device__ __forceinline__ f32x4 mfma16(short8 a, short8 b, f32x4 c) {
    return __builtin_amdgcn_mfma_f32_16x16x32_bf16(a, b, c, 0, 0, 0);
}
static __device__ __forceinline__ short f2bf(float f) {
    __hip_bfloat16 h = __float2bfloat16(f);
    return *reinterpret_cast<short*>(&h);
}

// Fragment-packed layout: P[(tile*KG + kg)*64 + lane] (short8 units).
#define FRAG(P, tile, KG, kg, l) ((P) + (((size_t)((tile)*(KG) + (kg)))*64 + (l))*8)

// ---------------------------------------------------------------------------
// qproj from an LDS row (stride-268 f32): thread handles one (s,h).
// ---------------------------------------------------------------------------
static __device__ __forceinline__ void qproj_row(
        const float* __restrict__ xrow,
        const float* __restrict__ th,
        int b, int s, int h,
        short* __restrict__ PQ, short* __restrict__ PT) {
    float v[DKK];
    float cum = __cosf(xrow[h * DKK + 0] + th[0]);
    float prod1 = 1.0f;
    #pragma unroll
    for (int j = 1; j < DKK; ++j) {
        float c = __cosf(xrow[h * DKK + j] + th[j]);
        cum *= c;
        prod1 *= c;
        v[j] = cum;
    }
    v[0] = prod1;
    short* pq = PQ + (size_t)b * SS * EE;
    int stile = s >> 4, lr = s & 15;
    #pragma unroll
    for (int lg = 0; lg < 4; ++lg) {
        short8 u;
        #pragma unroll
        for (int j = 0; j < 8; ++j) u[j] = f2bf(v[lg*8 + j]);
        *(short8*)FRAG(pq, stile*8 + h, 1, 0, lg*16 + lr) = u;
    }
    short* pt = PT + (size_t)b * SS * EE;
    int kt = s >> 5, lgs = (s >> 3) & 3, j0 = s & 7;
    #pragma unroll
    for (int j = 0; j < DKK; ++j) {
        int e = h * DKK + j;
        FRAG(pt, e >> 4, 32, kt, lgs*16 + (e & 15))[j0] = f2bf(v[j]);
    }
}

// ---------------------------------------------------------------------------
// Kernel 1: MERGED prep. bid<2304: weight transpose/pack. bid>=2304: embed +
// pos-encoding + layer-0 qproj (16 tokens/block, 256 thr).
// ---------------------------------------------------------------------------
__global__ __launch_bounds__(256) void k_prep(
        const float* __restrict__ W1, const float* __restrict__ W2,
        const float* __restrict__ Wc,
        short* __restrict__ W1P, short* __restrict__ W2P, short* __restrict__ WcP,
        const int* __restrict__ tokens, const float* __restrict__ emb,
        const float* __restrict__ theta_q,
        float* __restrict__ x, short* __restrict__ PQ, short* __restrict__ PT) {
    __shared__ float shmem[16 * 268];
    const int t = threadIdx.x;
    if (blockIdx.x < 2304) {
        // ---- trall ----
        int bid = blockIdx.x;
        int lyr = bid / 576, rem = bid % 576;
        const float* in; short* out; int R, C, tile;
        if (rem < 256)      { in = W1 + (size_t)lyr*NQQ*FF; out = W1P + (size_t)lyr*FF*NQQ; R = NQQ; C = FF;  tile = rem; }
        else if (rem < 512) { in = W2 + (size_t)lyr*FF*EE;  out = W2P + (size_t)lyr*EE*FF;  R = FF;  C = EE;  tile = rem - 256; }
        else                { in = Wc + (size_t)lyr*EE*EE;  out = WcP + (size_t)lyr*EE*EE;  R = EE;  C = EE;  tile = rem - 512; }
        const int KG = R >> 5;
        int tiles_c = C >> 5;
        int tc = tile % tiles_c, tr = tile / tiles_c;
        float (*tl)[33] = (float(*)[33])shmem;
        int rr = t >> 5, cc = t & 31;
        #pragma unroll
        for (int i = 0; i < 4; ++i)
            tl[rr + i*8][cc] = in[(size_t)(tr*32 + rr + i*8) * C + tc*32 + cc];
        __syncthreads();
        int ro = t >> 3, co = (t & 7) * 4;
        int n = tc*32 + ro;
        int k = tr*32 + co;
        int ntile = n >> 4, lr = n & 15;
        int kg = k >> 5, lg = (k & 31) >> 3, j0 = k & 7;
        s16x4 v;
        v[0] = f2bf(tl[co + 0][ro]);
        v[1] = f2bf(tl[co + 1][ro]);
        v[2] = f2bf(tl[co + 2][ro]);
        v[3] = f2bf(tl[co + 3][ro]);
        *(s16x4*)(FRAG(out, ntile, KG, kg, lg*16 + lr) + j0) = v;
    } else {
        // ---- embed + qproj(layer 0), 16 tokens ----
        int blk = blockIdx.x - 2304;
        int bsw = blk & 7, local = blk >> 3;        // batch -> XCD
        int tok0 = bsw * SS + local * 16;
        {
            int r = t >> 4, c0 = (t & 15) * 16;
            int bs = tok0 + r;
            int s  = bs & (SS - 1);
            int tok = tokens[bs];
            const float* er = emb + (size_t)tok * EE + c0;
            float vals[16];
            #pragma unroll
            for (int i = 0; i < 16; ++i) {
                int col = c0 + i;
                int i2 = col >> 1;
                float div = __expf(-(float)(2 * i2) * (logf(10000.0f) / (float)EE));
                float ang = (float)s * div;
                float pe = (col & 1) ? __cosf(ang) : __sinf(ang);
                vals[i] = er[i] + pe;
                shmem[r * 268 + col] = vals[i];
            }
            float* xg = x + (size_t)bs * EE + c0;
            #pragma unroll
            for (int i4 = 0; i4 < 4; ++i4)
                *(float4*)(xg + i4 * 4) = *(const float4*)&vals[i4 * 4];
        }
        __syncthreads();
        if (t < 128) {
            int sl = t >> 3, h = t & 7;
            int bs = tok0 + sl;
            qproj_row(&shmem[sl * 268], theta_q + h * DKK,
                      bs >> 10, bs & (SS - 1), h, PQ, PT);
        }
    }
}

// ---------------------------------------------------------------------------
// Kernel 3: attention — R12 structure (best known): 4 waves, KV-split,
// 2-slot additive merge, no online softmax, XCD-swizzled.
// ---------------------------------------------------------------------------
__global__ __launch_bounds__(256) void k_attn7(const short* __restrict__ PQ,
                                               const short* __restrict__ PT,
                                               short* __restrict__ YP) {
    const int b   = blockIdx.x & 7;       // batch -> XCD
    const int qt  = blockIdx.x >> 3;
    const int tid = threadIdx.x;
    const int w   = tid >> 6;
    const int l   = tid & 63;
    const int lr  = l & 15, lg = l >> 4;
    const short* pq = PQ + (size_t)b * SS * EE;
    const short* pt = PT + (size_t)b * SS * EE;

    __shared__ float accP[2][16][264];
    __shared__ float lsL[4][16];
    __shared__ short wlds[4][16 * 40];

    short8 qf[8];
    #pragma unroll
    for (int kg = 0; kg < 8; ++kg)
        qf[kg] = *(const short8*)FRAG(pq, qt*8 + kg, 1, 0, l);

    f32x4 acc[16];
    #pragma unroll
    for (int i = 0; i < 16; ++i) acc[i] = f32x4{0.f, 0.f, 0.f, 0.f};
    float ls[4] = {0.f, 0.f, 0.f, 0.f};
    const float scale = 0.17677669529663687f;
    short* wl = wlds[w];

    for (int i = 0; i < 8; ++i) {
        const int kt = w + 4 * i;
        short8 sb0[8], sb1[8];
        #pragma unroll
        for (int kg = 0; kg < 8; ++kg) {
            sb0[kg] = *(const short8*)FRAG(pq, (2*kt)*8   + kg, 1, 0, l);
            sb1[kg] = *(const short8*)FRAG(pq, (2*kt+1)*8 + kg, 1, 0, l);
        }
        f32x4 s0a = {0.f,0.f,0.f,0.f}, s0b = {0.f,0.f,0.f,0.f};
        f32x4 s1a = {0.f,0.f,0.f,0.f}, s1b = {0.f,0.f,0.f,0.f};
        #pragma unroll
        for (int kg = 0; kg < 4; ++kg) {
            s0a = mfma16(qf[kg], sb0[kg], s0a);
            s1a = mfma16(qf[kg], sb1[kg], s1a);
        }
        #pragma unroll
        for (int kg = 4; kg < 8; ++kg) {
            s0b = mfma16(qf[kg], sb0[kg], s0b);
            s1b = mfma16(qf[kg], sb1[kg], s1b);
        }
        short8 pvb0[8];
        #pragma unroll
        for (int nt = 0; nt < 8; ++nt)
            pvb0[nt] = *(const short8*)FRAG(pt, nt, 32, kt, l);

        #pragma unroll
        for (int r = 0; r < 4; ++r) {
            float p0 = __expf((s0a[r] + s0b[r]) * scale);
            float p1 = __expf((s1a[r] + s1b[r]) * scale);
            ls[r] += p0 + p1;
            int q = lg * 4 + r;
            wl[q * 40 + lr]      = f2bf(p0);
            wl[q * 40 + 16 + lr] = f2bf(p1);
        }
        short8 pa = *(const short8*)(wl + lr * 40 + lg * 8);
        short8 pvb1[8];
        #pragma unroll
        for (int nt = 0; nt < 8; ++nt)
            pvb1[nt] = *(const short8*)FRAG(pt, 8 + nt, 32, kt, l);
        #pragma unroll
        for (int nt = 0; nt < 8; ++nt)
            acc[nt] = mfma16(pa, pvb0[nt], acc[nt]);
        #pragma unroll
        for (int nt = 0; nt < 8; ++nt)
            acc[8 + nt] = mfma16(pa, pvb1[nt], acc[8 + nt]);
    }

    #pragma unroll
    for (int r = 0; r < 4; ++r) {
        ls[r] += __shfl_xor(ls[r], 1);
        ls[r] += __shfl_xor(ls[r], 2);
        ls[r] += __shfl_xor(ls[r], 4);
        ls[r] += __shfl_xor(ls[r], 8);
    }
    if (lr == 0) {
        #pragma unroll
        for (int r = 0; r < 4; ++r)
            lsL[w][lg * 4 + r] = ls[r];
    }

    if (w >= 2) {
        #pragma unroll
        for (int nt = 0; nt < 16; ++nt)
            #pragma unroll
            for (int r = 0; r < 4; ++r)
                accP[w - 2][lg * 4 + r][nt * 16 + lr] = acc[nt][r];
    }
    __syncthreads();
    if (w < 2) {
        #pragma unroll
        for (int nt = 0; nt < 16; ++nt)
            #pragma unroll
            for (int r = 0; r < 4; ++r)
                accP[w][lg * 4 + r][nt * 16 + lr] += acc[nt][r];
    }
    __syncthreads();

    const int q = tid >> 4, c = tid & 15;
    float L = lsL[0][q] + lsL[1][q] + lsL[2][q] + lsL[3][q];
    float inv = 1.0f / L;
    short ov[16];
    #pragma unroll
    for (int j = 0; j < 4; ++j) {
        float4 a  = *(const float4*)&accP[0][q][c * 16 + j * 4];
        float4 bb = *(const float4*)&accP[1][q][c * 16 + j * 4];
        ov[j*4 + 0] = f2bf((a.x + bb.x) * inv);
        ov[j*4 + 1] = f2bf((a.y + bb.y) * inv);
        ov[j*4 + 2] = f2bf((a.z + bb.z) * inv);
        ov[j*4 + 3] = f2bf((a.w + bb.w) * inv);
    }
    short* yb = YP + (size_t)b * SS * EE;
    int kgo = c >> 1, lgo = (c & 1) * 2;
    *(short8*)FRAG(yb, qt*8 + kgo, 1, 0, lgo*16 + q)     = *(const short8*)&ov[0];
    *(short8*)FRAG(yb, qt*8 + kgo, 1, 0, (lgo+1)*16 + q) = *(const short8*)&ov[8];
}

// ---------------------------------------------------------------------------
// Kernel 4: FUSED wc+LN1 + FFN+LN2 + next-layer qproj / head-partials.
// 1024 threads / 16 waves. NEW: W2 fragment loads issued at the TOP of each
// fc iteration (before GEMM1 + barrier) — cross-barrier prefetch the
// compiler can't do; hides the post-barrier L2 load storm under GEMM1.
// ---------------------------------------------------------------------------
__global__ __launch_bounds__(1024) void k_wcffnq(
        const short* __restrict__ YP, const short* __restrict__ WcP,
        const float* __restrict__ bc, const float* __restrict__ g1,
        const float* __restrict__ bn1,
        const float* __restrict__ tf, const short* __restrict__ W1P,
        const float* __restrict__ b1, const short* __restrict__ W2P,
        const float* __restrict__ b2, const float* __restrict__ g2,
        const float* __restrict__ bn2,
        float* __restrict__ x,
        const float* __restrict__ theta_q, short* __restrict__ PQ,
        short* __restrict__ PT, float* __restrict__ hpart, int has_next) {
    const int t = threadIdx.x, w = t >> 6, l = t & 63;   // w: 0..15
    const int lr = l & 15, lg = l >> 4;
    const int b = blockIdx.x & 7;            // batch -> XCD
    const int local = blockIdx.x >> 3;       // 0..31
    const int tok0 = b * SS + local * 32;
    const int qt0 = local * 2;

    __shared__ __align__(16) char smem[34304 + 16384 + 16384];
    float* outw = (float*)smem;                    // [32][268] f32
    char*  qls  = smem + 34304;                    // [32][256] bf16 swizzled
    char*  hls  = smem + 34304 + 16384;            // [32][256] bf16 swizzled
    float* fout = (float*)(smem + 34304);          // [32][256] f32 overlay

    const short* yb = YP + (size_t)b * SS * EE;

    // ---------- Phase A: wc GEMM ----------
    {
        const int wg = w >> 3, wn8 = w & 7;
        short8 af[8];
        #pragma unroll
        for (int kg = 0; kg < 8; ++kg)
            af[kg] = *(const short8*)FRAG(yb, (qt0 + wg)*8 + kg, 1, 0, l);
        f32x4 acc[2];
        acc[0] = f32x4{0.f,0.f,0.f,0.f};
        acc[1] = f32x4{0.f,0.f,0.f,0.f};
        #pragma unroll
        for (int nt = 0; nt < 2; ++nt) {
            #pragma unroll
            for (int kg = 0; kg < 8; ++kg) {
                short8 bv = *(const short8*)FRAG(WcP, wn8*2 + nt, 8, kg, l);
                acc[nt] = mfma16(af[kg], bv, acc[nt]);
            }
        }
        #pragma unroll
        for (int nt = 0; nt < 2; ++nt) {
            int e = wn8 * 32 + nt * 16 + lr;
            float bce = bc[e];
            #pragma unroll
            for (int r = 0; r < 4; ++r)
                outw[(wg*16 + lg*4 + r) * 268 + e] = acc[nt][r] + bce;
        }
    }
    __syncthreads();

    // ---------- Phase A epilogue: residual+LN1 -> x1; stage q into qls ------
    #pragma unroll
    for (int j = 0; j < 2; ++j) {
        int q = w * 2 + j;
        float4 v  = *(float4*)&outw[q * 268 + l * 4];
        float4 xv = *(const float4*)(x + (size_t)(tok0 + q) * EE + l * 4);
        v.x += xv.x; v.y += xv.y; v.z += xv.z; v.w += xv.w;
        float s = v.x + v.y + v.z + v.w;
        for (int off = 32; off > 0; off >>= 1) s += __shfl_xor(s, off);
        float mean = s * (1.0f / EE);
        float4 d;
        d.x = v.x - mean; d.y = v.y - mean; d.z = v.z - mean; d.w = v.w - mean;
        float s2 = d.x*d.x + d.y*d.y + d.z*d.z + d.w*d.w;
        for (int off = 32; off > 0; off >>= 1) s2 += __shfl_xor(s2, off);
        float inv = rsqrtf(s2 * (1.0f / EE) + 1e-5f);
        float4 gv  = *(const float4*)(g1  + l * 4);
        float4 bnv = *(const float4*)(bn1 + l * 4);
        float4 o;
        o.x = d.x * inv * gv.x + bnv.x;
        o.y = d.y * inv * gv.y + bnv.y;
        o.z = d.z * inv * gv.z + bnv.z;
        o.w = d.w * inv * gv.w + bnv.w;
        *(float4*)&outw[q * 268 + l * 4] = o;
        float4 tv = *(const float4*)(tf + l * 4);
        float q0 = __cosf(o.x) * __cosf(tv.x);
        float q1 = __cosf(o.y) * __cosf(tv.y);
        float q2 = __cosf(o.z) * __cosf(tv.z);
        float q3 = __cosf(o.w) * __cosf(tv.w);
        int byte = (q * 512 + l * 8) ^ ((q & 7) << 4);
        *(unsigned*)(qls + byte) =
            (unsigned)(unsigned short)f2bf(q0) | ((unsigned)(unsigned short)f2bf(q1) << 16);
        *(unsigned*)(qls + byte + 4) =
            (unsigned)(unsigned short)f2bf(q2) | ((unsigned)(unsigned short)f2bf(q3) << 16);
    }
    __syncthreads();

    // ---------- Phase B: FFN (f-chunked) with W2 cross-barrier prefetch ----
    f32x4 acc2[2];
    acc2[0] = f32x4{0.f,0.f,0.f,0.f};
    acc2[1] = f32x4{0.f,0.f,0.f,0.f};

    for (int fc = 0; fc < 4; ++fc) {
        // PREFETCH: W2 fragments for this fc, consumed only after the
        // barrier below — loads fly during GEMM1 compute + barrier wait.
        short8 w2f[8];
        #pragma unroll
        for (int k8 = 0; k8 < 8; ++k8)
            w2f[k8] = *(const short8*)FRAG(W2P, w, 32, fc*8 + k8, l);

        f32x4 acc1[2];
        acc1[0] = f32x4{0.f,0.f,0.f,0.f};
        acc1[1] = f32x4{0.f,0.f,0.f,0.f};
        #pragma unroll
        for (int kg = 0; kg < 8; ++kg) {
            int ca = (kg*32 + lg*8) * 2;
            short8 a0 = *(const short8*)(qls + ((lr*512      + ca) ^ ((lr & 7) << 4)));
            short8 a1 = *(const short8*)(qls + (((16+lr)*512 + ca) ^ ((lr & 7) << 4)));
            short8 bv = *(const short8*)FRAG(W1P, fc*16 + w, 8, kg, l);
            acc1[0] = mfma16(a0, bv, acc1[0]);
            acc1[1] = mfma16(a1, bv, acc1[1]);
        }
        {
            int fcol = w * 16 + lr;              // col within 256-f chunk
            float bb = b1[fc * 256 + fcol];
            #pragma unroll
            for (int mt = 0; mt < 2; ++mt) {
                #pragma unroll
                for (int r = 0; r < 4; ++r) {
                    int tq = mt * 16 + lg * 4 + r;
                    float hv = fmaxf(acc1[mt][r] + bb, 0.0f);
                    int byte = (tq * 512 + fcol * 2) ^ ((tq & 7) << 4);
                    *(short*)(hls + byte) = f2bf(hv);
                }
            }
        }
        __syncthreads();
        #pragma unroll
        for (int k8 = 0; k8 < 8; ++k8) {
            int ca = (k8*32 + lg*8) * 2;
            short8 h0 = *(const short8*)(hls + ((lr*512      + ca) ^ ((lr & 7) << 4)));
            short8 h1 = *(const short8*)(hls + (((16+lr)*512 + ca) ^ ((lr & 7) << 4)));
            acc2[0] = mfma16(h0, w2f[k8], acc2[0]);
            acc2[1] = mfma16(h1, w2f[k8], acc2[1]);
        }
        __syncthreads();
    }

    {   // fout overlay (qls+hls free now)
        int e = w * 16 + lr;
        float b2e = b2[e];
        #pragma unroll
        for (int mt = 0; mt < 2; ++mt)
            #pragma unroll
            for (int r = 0; r < 4; ++r)
                fout[(mt*16 + lg*4 + r) * 256 + e] = acc2[mt][r] + b2e;
    }
    __syncthreads();

    // ---------- Phase B epilogue: residual(x1)+LN2 -> x2 ----------
    #pragma unroll
    for (int j = 0; j < 2; ++j) {
        int q = w * 2 + j;
        float4 v  = *(float4*)&fout[q * 256 + l * 4];
        float4 x1 = *(float4*)&outw[q * 268 + l * 4];
        v.x += x1.x; v.y += x1.y; v.z += x1.z; v.w += x1.w;
        float s = v.x + v.y + v.z + v.w;
        for (int off = 32; off > 0; off >>= 1) s += __shfl_xor(s, off);
        float mean = s * (1.0f / EE);
        float4 d;
        d.x = v.x - mean; d.y = v.y - mean; d.z = v.z - mean; d.w = v.w - mean;
        float s2 = d.x*d.x + d.y*d.y + d.z*d.z + d.w*d.w;
        for (int off = 32; off > 0; off >>= 1) s2 += __shfl_xor(s2, off);
        float inv = rsqrtf(s2 * (1.0f / EE) + 1e-5f);
        float4 gv  = *(const float4*)(g2  + l * 4);
        float4 bnv = *(const float4*)(bn2 + l * 4);
        float4 o;
        o.x = d.x * inv * gv.x + bnv.x;
        o.y = d.y * inv * gv.y + bnv.y;
        o.z = d.z * inv * gv.z + bnv.z;
        o.w = d.w * inv * gv.w + bnv.w;
        if (has_next)
            *(float4*)(x + (size_t)(tok0 + q) * EE + l * 4) = o;
        *(float4*)&outw[q * 268 + l * 4] = o;
    }
    __syncthreads();

    if (has_next) {
        // ---------- Phase C: next-layer qproj from x2 (LDS) ----------
        if (t < 256) {
            int sl = t >> 3, h = t & 7;
            int bs = tok0 + sl;
            qproj_row(&outw[sl * 268], theta_q + h * DKK,
                      bs >> 10, bs & (SS - 1), h, PQ, PT);
        }
    } else {
        // ---------- Phase C': head partial sums from x2 (LDS) ----------
        if (t < 256) {
            float acc = 0.0f;
            #pragma unroll 8
            for (int r = 0; r < 32; ++r)
                acc += outw[r * 268 + t];
            hpart[(size_t)(b * 32 + local) * EE + t] = acc;
        }
    }
}

// ---------------------------------------------------------------------------
// Kernel 6: head reduce + classifier. grid = B blocks, 256 threads.
// ---------------------------------------------------------------------------
__global__ __launch_bounds__(256) void k_head2(const float* __restrict__ hpart,
                                               const float* __restrict__ Wcls,
                                               const float* __restrict__ bcls,
                                               float* __restrict__ out) {
    int b = blockIdx.x;
    int t = threadIdx.x;
    __shared__ float xm[EE];
    float acc = 0.0f;
    #pragma unroll 8
    for (int j = 0; j < 32; ++j)
        acc += hpart[(size_t)(b * 32 + j) * EE + t];
    xm[t] = acc * (1.0f / (float)SS);
    __syncthreads();
    if (t < CC) {
        float a = bcls[t];
        #pragma unroll 8
        for (int e = 0; e < EE; ++e) a += xm[e] * Wcls[e * CC + t];
        out[b * CC + t] = a;
    }
}

// ---------------------------------------------------------------------------
extern "C" void kernel_launch(void* const* d_in, const int* in_sizes, int n_in,
                              void* d_out, int out_size, void* d_ws, size_t ws_size,
                              hipStream_t stream) {
    (void)in_sizes; (void)n_in; (void)out_size; (void)ws_size;
    const int*   tokens     = (const int*)d_in[0];
    const float* emb        = (const float*)d_in[1];
    const float* theta_attn = (const float*)d_in[2];
    const float* Wc         = (const float*)d_in[3];
    const float* bc         = (const float*)d_in[4];
    const float* g1         = (const float*)d_in[5];
    const float* bn1        = (const float*)d_in[6];
    const float* theta_ffn  = (const float*)d_in[7];
    const float* W1         = (const float*)d_in[8];
    const float* b1         = (const float*)d_in[9];
    const float* W2         = (const float*)d_in[10];
    const float* b2         = (const float*)d_in[11];
    const float* g2         = (const float*)d_in[12];
    const float* bn2        = (const float*)d_in[13];
    const float* Wcls       = (const float*)d_in[14];
    const float* bcls       = (const float*)d_in[15];
    float* out = (float*)d_out;

    const size_t nTok = (size_t)BB * SS * EE;     // 2M
    float* x     = (float*)d_ws;                  // 8 MB
    short* PQ    = (short*)(x + nTok);            // 4 MB
    short* PT    = PQ  + nTok;                    // 4 MB
    short* YP    = PT  + nTok;                    // 4 MB
    short* W1P   = YP  + nTok;                    // 2 MB
    short* W2P   = W1P + (size_t)LL * FF * NQQ;   // 2 MB
    short* WcP   = W2P + (size_t)LL * EE * FF;    // 0.5 MB
    float* hpart = (float*)(WcP + (size_t)LL * EE * EE);  // 256 KB

    k_prep<<<2304 + 512, 256, 0, stream>>>(
        W1, W2, Wc, W1P, W2P, WcP, tokens, emb, theta_attn, x, PQ, PT);

    for (int l = 0; l < LL; ++l) {
        int has_next = (l + 1 < LL) ? 1 : 0;
        const float* thq = theta_attn + (size_t)(has_next ? l + 1 : 0) * HH * DKK;
        k_attn7<<<BB * 64, 256, 0, stream>>>(PQ, PT, YP);
        k_wcffnq<<<(BB * SS) / 32, 1024, 0, stream>>>(
            YP, WcP + (size_t)l * EE * EE, bc + (size_t)l * EE,
            g1 + (size_t)l * EE, bn1 + (size_t)l * EE,
            theta_ffn + (size_t)l * NQQ,
            W1P + (size_t)l * FF * NQQ, b1 + (size_t)l * FF,
            W2P + (size_t)l * EE * FF, b2 + (size_t)l * EE,
            g2 + (size_t)l * EE, bn2 + (size_t)l * EE,
            x, thq, PQ, PT, hpart, has_next);
    }

    k_head2<<<BB, 256, 0, stream>>>(hpart, Wcls, bcls, out);
}